// Round 8
// baseline (45.215 us; speedup 1.0000x reference)
//
#include <hip/hip_runtime.h>

// Camera ISP fused: mosaic -> 3x3 gauss blur -> 17-knot LUT -> +noise ->
// sparse 5x5 demosaic -> bayer-parity select -> clip.
// Round 7: R6 rolling-register pipeline, TDS 16 -> 8 to double the grid
// (1024 blocks, 16 waves/CU): occupancy was grid-limited at 18.6%.

#define TDS 8      // output rows per wave

typedef float f4u __attribute__((ext_vector_type(4), aligned(16)));

struct HB { float hb0, hb1, hb2, hb3, hh0, hh1; };

__device__ __forceinline__ int refl(int i, int n) {
    return i < 0 ? -i : (i >= n ? 2 * n - 2 - i : i);
}

__device__ __forceinline__ float clip01(float x) {
    return fminf(fmaxf(x * (1.0f / 255.0f), 0.0f), 1.0f);
}

__global__ __launch_bounds__(256, 4) void camera_kernel(
    const float* __restrict__ im, const float* __restrict__ yp,
    const float* __restrict__ noise, float* __restrict__ out,
    int H, int W)
{
    __shared__ float2 s_tab[4][48];   // per-wave LUT copy (no block barrier)

    const int tid  = threadIdx.x;
    const int wv   = tid >> 6;
    const int lane = tid & 63;
    const int b    = blockIdx.z;

    const int stripes = W >> 8;                  // 256-px stripes
    const int slot    = blockIdx.x * 4 + wv;
    const int stripe  = slot % stripes;
    const int gy0     = (slot / stripes) * TDS;  // even
    const int gx0     = stripe << 8;             // even
    const int x0      = gx0 + 4 * lane;

    const size_t HW = (size_t)H * W;
    const float* p0  = im + (size_t)b * 3 * HW;  // ch0 plane
    const float* p1  = p0 + HW;                  // ch1 plane
    const float* nzb = noise + (size_t)b * HW;

    if (lane < 48) {
        int ch = lane >> 4, i = lane & 15;
        s_tab[wv][lane] = make_float2(yp[ch * 17 + i], yp[ch * 17 + i + 1]);
    }
    asm volatile("s_waitcnt lgkmcnt(0)" ::: "memory");
    const float2* tabw = s_tab[wv];

    const bool l0   = (lane == 0), l63 = (lane == 63);
    const bool lInt = l0  && (gx0 != 0);         // interior stripe boundary
    const bool rInt = l63 && (x0 + 4 != W);
    const bool eInt = lInt || rInt;
    const bool eAny = l0 || l63;
    const int  xe   = l0 ? x0 - 4 : x0 + 4;      // edge mosaic halo base
    const int  xen  = l0 ? x0 - 2 : x0 + 4;      // edge noise halo base

    const float g0 = 0.04038794f;   // 1D gauss tail (sigma=0.4, normalized)
    const float g1 = 0.91922413f;   // 1D gauss center

    auto itp = [&](float tv, int ch) -> float {  // LUT interp, input x16 scale
        float s = tv * 16.0f;
        int i = (int)s; i = i < 0 ? 0 : (i > 15 ? 15 : i);
        float2 p = tabw[ch * 16 + i];
        return fmaf(s - (float)i, p.y - p.x, p.x);
    };

    // load mosaic row t (reflect-mapped), return hblur[x0..x0+3] + edge halo
    auto mosrow = [&](int t) -> HB {
        int yr = refl(t, H);                     // parity-preserving
        const float* pe = (t & 1) ? p0 : p1;     // plane for even cols
        const float* re = pe + (size_t)yr * W;
        const float* ro = re + HW;               // plane for odd cols
        f4u a  = *(const f4u*)(re + x0);
        f4u bq = *(const f4u*)(ro + x0);
        float m0 = a.x, m1 = bq.y, m2 = a.z, m3 = bq.w;  // cols x0..x0+3
        float ml = __shfl_up(m3, 1, 64);         // col x0-1 (from lane-1)
        float mr = __shfl_down(m0, 1, 64);       // col x0+4 (from lane+1)
        float me0 = 0.f, me1 = 0.f, me2 = 0.f, me3 = 0.f;
        if (eInt) {                              // neighbor-stripe 4 cols
            f4u ae = *(const f4u*)(re + xe);
            f4u be = *(const f4u*)(ro + xe);
            me0 = ae.x; me1 = be.y; me2 = ae.z; me3 = be.w;
        }
        if (l0)  ml = lInt ? me3 : m1;           // reflect: col -1 -> 1
        if (l63) mr = rInt ? me0 : m2;           // reflect: col W -> W-2
        HB h;
        h.hb0 = fmaf(g0, ml + m1, g1 * m0);
        h.hb1 = fmaf(g0, m0 + m2, g1 * m1);
        h.hb2 = fmaf(g0, m1 + m3, g1 * m2);
        h.hb3 = fmaf(g0, m2 + mr, g1 * m3);
        // edge-halo hblur (lane0: cols x0-2,x0-1 ; lane63: cols x0+4,x0+5)
        float hL0 = fmaf(g0, me1 + me3, g1 * me2);
        float hL1 = fmaf(g0, me2 + m0,  g1 * me3);
        float hR0 = fmaf(g0, m3 + me1,  g1 * me0);
        float hR1 = fmaf(g0, me0 + me2, g1 * me1);
        h.hh0 = l0 ? hL0 : hR0;
        h.hh1 = l0 ? hL1 : hR1;
        return h;
    };

    float ring[5][8];                            // 5 noisy rows x cols x0-2..x0+5
    HB hA = mosrow(gy0 - 3);
    HB hB = mosrow(gy0 - 2);
    const size_t outb = (size_t)b * 3 * HW;

    #pragma unroll
    for (int k = 0; k < TDS + 4; ++k) {
        const int r = gy0 - 2 + k;               // noisy row produced this iter
        HB hC = mosrow(r + 1);
        // vertical blur (rows r-1, r, r+1)
        float tb0 = fmaf(g0, hA.hb0 + hC.hb0, g1 * hB.hb0);
        float tb1 = fmaf(g0, hA.hb1 + hC.hb1, g1 * hB.hb1);
        float tb2 = fmaf(g0, hA.hb2 + hC.hb2, g1 * hB.hb2);
        float tb3 = fmaf(g0, hA.hb3 + hC.hb3, g1 * hB.hb3);
        float th0 = fmaf(g0, hA.hh0 + hC.hh0, g1 * hB.hh0);
        float th1 = fmaf(g0, hA.hh1 + hC.hh1, g1 * hB.hh1);
        // LUT interp; row parity = k&1 (gy0 even)
        const int chE = (k & 1) ? 0 : 1;         // channel for even cols
        const int chO = chE + 1;
        float c0 = itp(tb0, chE), c1 = itp(tb1, chO);
        float c2 = itp(tb2, chE), c3 = itp(tb3, chO);
        // noise
        int yr = refl(r, H);
        const float* nzr = nzb + (size_t)yr * W;
        f4u nz = *(const f4u*)(nzr + x0);
        float2 nze = make_float2(0.f, 0.f);
        if (eInt) nze = *(const float2*)(nzr + xen);
        c0 += nz.x; c1 += nz.y; c2 += nz.z; c3 += nz.w;
        // edge-halo noisy (2 px, exec-masked to lanes 0/63)
        float e0 = 0.f, e1 = 0.f;
        if (eAny) { e0 = itp(th0, chE) + nze.x; e1 = itp(th1, chO) + nze.y; }
        // horizontal halo cols x0-2,x0-1 / x0+4,x0+5
        float hl0 = __shfl_up(c2, 1, 64);
        float hl1 = __shfl_up(c3, 1, 64);
        float hr0 = __shfl_down(c0, 1, 64);
        float hr1 = __shfl_down(c1, 1, 64);
        if (l0)  { hl0 = lInt ? e0 : c2;  hl1 = lInt ? e1 : c1; }  // reflect -2,-1 -> 2,1
        if (l63) { hr0 = rInt ? e0 : c2;  hr1 = rInt ? e1 : c1; }  // reflect W,W+1 -> W-2,W-3
        ring[k % 5][0] = hl0; ring[k % 5][1] = hl1;
        ring[k % 5][2] = c0;  ring[k % 5][3] = c1;
        ring[k % 5][4] = c2;  ring[k % 5][5] = c3;
        ring[k % 5][6] = hr0; ring[k % 5][7] = hr1;
        hA = hB; hB = hC;

        if (k >= 4) {                            // demosaic row y = gy0+k-4
            const int y = gy0 + k - 4;           // parity = k&1
            float Rv[4], Gv[4], Bv[4];
            #pragma unroll
            for (int j = 0; j < 4; ++j) {
                const int cj = 2 + j;
                float c    = ring[(k - 2) % 5][cj];
                float ax1x = ring[(k - 2) % 5][cj - 1] + ring[(k - 2) % 5][cj + 1];
                float ax2x = ring[(k - 2) % 5][cj - 2] + ring[(k - 2) % 5][cj + 2];
                float ax1y = ring[(k - 3) % 5][cj] + ring[(k - 1) % 5][cj];
                float diag = ring[(k - 3) % 5][cj - 1] + ring[(k - 3) % 5][cj + 1]
                           + ring[(k - 1) % 5][cj - 1] + ring[(k - 1) % 5][cj + 1];
                float ax2y = ring[(k - 4) % 5][cj] + ring[k % 5][cj];
                const bool xO = (j & 1) != 0;
                const bool yO = (k & 1) != 0;
                float R, G, Bc;
                if (!yO && !xO) {        // p00: R=v, G=raw, B=h
                    float hh = (0.5f * ax2y - diag - ax2x + 4.f * ax1x + 5.f * c) * 0.125f;
                    float vv = (0.5f * ax2x - diag - ax2y + 4.f * ax1y + 5.f * c) * 0.125f;
                    R = vv; G = c; Bc = hh;
                } else if (!yO && xO) {  // p01: R=d, G=g, B=raw
                    float gg = (2.f * (ax1y + ax1x) - ax2y - ax2x + 4.f * c) * 0.125f;
                    float dd = (2.f * diag - 1.5f * (ax2y + ax2x) + 6.f * c) * 0.125f;
                    R = dd; G = gg; Bc = c;
                } else if (yO && !xO) {  // p10: R=raw, G=g, B=d
                    float gg = (2.f * (ax1y + ax1x) - ax2y - ax2x + 4.f * c) * 0.125f;
                    float dd = (2.f * diag - 1.5f * (ax2y + ax2x) + 6.f * c) * 0.125f;
                    R = c; G = gg; Bc = dd;
                } else {                 // p11: R=h, G=raw, B=v
                    float hh = (0.5f * ax2y - diag - ax2x + 4.f * ax1x + 5.f * c) * 0.125f;
                    float vv = (0.5f * ax2x - diag - ax2y + 4.f * ax1y + 5.f * c) * 0.125f;
                    R = hh; G = c; Bc = vv;
                }
                Rv[j] = clip01(R); Gv[j] = clip01(G); Bv[j] = clip01(Bc);
            }
            size_t o = outb + (size_t)y * W + x0;
            *(f4u*)(out + o)          = (f4u){Rv[0], Rv[1], Rv[2], Rv[3]};
            *(f4u*)(out + o + HW)     = (f4u){Gv[0], Gv[1], Gv[2], Gv[3]};
            *(f4u*)(out + o + 2 * HW) = (f4u){Bv[0], Bv[1], Bv[2], Bv[3]};
        }
    }
}

extern "C" void kernel_launch(void* const* d_in, const int* in_sizes, int n_in,
                              void* d_out, int out_size, void* d_ws, size_t ws_size,
                              hipStream_t stream) {
    const float* im    = (const float*)d_in[0];
    const float* yp    = (const float*)d_in[1];
    const float* noise = (const float*)d_in[2];
    float* out = (float*)d_out;

    const int H = 512, W = 512;
    const int B = in_sizes[2] / (H * W);         // noise is (B,1,H,W)

    const int stripes = W / 256;                 // 2
    const int slots   = stripes * (H / TDS);     // 128 wave-slots per image
    dim3 grid(slots / 4, 1, B);                  // 4 waves per 256-thread block
    camera_kernel<<<grid, 256, 0, stream>>>(im, yp, noise, out, H, W);
}